// Round 1
// baseline (842.641 us; speedup 1.0000x reference)
//
#include <hip/hip_runtime.h>

// Block-diagonal equivariant linear on MI355X.
// out[n, OFF + w*D + i] = ALPHA * sum_u x[n, OFF + u*D + i] * W[u, w]
//
// v2 strategy: deinterleave x into D bf16 planes in LDS at stage time
// (coalesced float4 global reads -> scalar bf16 LDS writes), so that
// A-fragments are single ds_read_b128 per MFMA k-step; re-interleave the
// output through an LDS f32 tile so global stores are coalesced float4.
// Replaces 8x ds_read_u16 per fragment and stride-D scattered dword stores.

typedef __attribute__((ext_vector_type(8))) short short8;
typedef __attribute__((ext_vector_type(4))) float floatx4;

#define ALPHA 0.08838834764831845f
#define FEAT 1152

__device__ inline unsigned short bf16_rne(float f) {
    unsigned int u = __float_as_uint(f);
    unsigned int r = u + 0x7fffu + ((u >> 16) & 1u);
    return (unsigned short)(r >> 16);
}

template <int D, int OFF, int MINBPC>
__launch_bounds__(256, MINBPC)
__global__ void eq_linear_kernel(const float* __restrict__ x,
                                 const float* __restrict__ wmat,
                                 float* __restrict__ out, int n) {
    constexpr int C   = 128 * D;        // columns in this irrep block
    constexpr int C4  = C / 4;
    constexpr int R   = 16;             // rows per workgroup (one M-tile)
    constexpr int AP  = 136;            // A-plane row pitch (elems, 272B -> 16B-slot rotation, <=2-way)
    constexpr int APL = R * AP + 8;     // plane stride incl. +16B skew (1092 dwords = 4 mod 32 banks)
    constexpr int OP  = C + 4;          // out-stage row pitch (dwords; 4 mod 32 -> quad rows 2-way max)

    __shared__ unsigned short xs[D * APL];              // D=5: 21.8 KB
    __shared__ float os[(D == 1) ? 1 : (R * OP)];       // D=5: 41.2 KB (total 63 KB -> 2 blk/CU)

    const int tid  = threadIdx.x;
    const int lane = tid & 63;
    const int wave = tid >> 6;
    const int l16  = lane & 15;
    const int quad = lane >> 4;
    const int rowbase = blockIdx.x * R;

    // ---- stage + deinterleave: coalesced float4 reads -> bf16 planes ----
    constexpr int ITERS = (R * C4) / 256;   // 2 / 6 / 10 for D = 1/3/5
#pragma unroll
    for (int it = 0; it < ITERS; ++it) {
        int idx = tid + it * 256;
        int r  = idx / C4;                  // compile-time divisor -> magic mul
        int c4 = idx - r * C4;
        float4 v = make_float4(0.f, 0.f, 0.f, 0.f);
        if (rowbase + r < n) {
            v = *(reinterpret_cast<const float4*>(
                  x + (size_t)(rowbase + r) * FEAT + OFF) + c4);
        }
        if (D == 1) {
            unsigned int p0 = (unsigned int)bf16_rne(v.x) | ((unsigned int)bf16_rne(v.y) << 16);
            unsigned int p1 = (unsigned int)bf16_rne(v.z) | ((unsigned int)bf16_rne(v.w) << 16);
            unsigned int* lp = reinterpret_cast<unsigned int*>(&xs[r * AP + c4 * 4]);
            lp[0] = p0;
            lp[1] = p1;
        } else {
            float vv[4] = {v.x, v.y, v.z, v.w};
#pragma unroll
            for (int j = 0; j < 4; ++j) {
                int c = 4 * c4 + j;
                int u = c / D;              // compile-time divisor
                int i = c - u * D;
                xs[i * APL + r * AP + u] = bf16_rne(vv[j]);
            }
        }
    }

    // ---- B fragments: W fp32 (L2-hot) -> bf16 regs; 2 n-tiles per wave ----
    short8 bfrag[2][4];
#pragma unroll
    for (int ntl = 0; ntl < 2; ++ntl) {
        int wcol = (wave * 2 + ntl) * 16 + l16;
#pragma unroll
        for (int k = 0; k < 4; ++k) {
            int u0 = k * 32 + quad * 8;
            short8 f;
#pragma unroll
            for (int j = 0; j < 8; ++j) {
                f[j] = (short)bf16_rne(wmat[(u0 + j) * 128 + wcol]);
            }
            bfrag[ntl][k] = f;
        }
    }

    __syncthreads();

    // ---- compute: per component i, A-frag = one ds_read_b128 ----
#pragma unroll
    for (int i = 0; i < D; ++i) {
        floatx4 acc[2] = {floatx4{0, 0, 0, 0}, floatx4{0, 0, 0, 0}};
#pragma unroll
        for (int k = 0; k < 4; ++k) {
            const short8 a = *reinterpret_cast<const short8*>(
                &xs[i * APL + l16 * AP + k * 32 + quad * 8]);
            acc[0] = __builtin_amdgcn_mfma_f32_16x16x32_bf16(a, bfrag[0][k], acc[0], 0, 0, 0);
            acc[1] = __builtin_amdgcn_mfma_f32_16x16x32_bf16(a, bfrag[1][k], acc[1], 0, 0, 0);
        }
        if (D == 1) {
            // already contiguous: direct coalesced stores
#pragma unroll
            for (int ntl = 0; ntl < 2; ++ntl) {
                int col = OFF + (wave * 2 + ntl) * 16 + l16;
#pragma unroll
                for (int r = 0; r < 4; ++r) {
                    int row = rowbase + quad * 4 + r;
                    if (row < n) out[(size_t)row * FEAT + col] = acc[ntl][r] * ALPHA;
                }
            }
        } else {
            // re-interleave through LDS (lane stride D dwords; gcd(D,32)=1 -> conflict-free)
#pragma unroll
            for (int ntl = 0; ntl < 2; ++ntl) {
                int wc = (wave * 2 + ntl) * 16 + l16;
#pragma unroll
                for (int r = 0; r < 4; ++r) {
                    os[(quad * 4 + r) * OP + wc * D + i] = acc[ntl][r] * ALPHA;
                }
            }
        }
    }

    // ---- drain out-tile: coalesced float4 global stores ----
    if (D > 1) {
        __syncthreads();
#pragma unroll
        for (int it = 0; it < ITERS; ++it) {
            int idx = tid + it * 256;
            int r  = idx / C4;
            int c4 = idx - r * C4;
            if (rowbase + r < n) {
                float4 v = *reinterpret_cast<const float4*>(&os[r * OP + 4 * c4]);
                *(reinterpret_cast<float4*>(
                      out + (size_t)(rowbase + r) * FEAT + OFF) + c4) = v;
            }
        }
    }
}

extern "C" void kernel_launch(void* const* d_in, const int* in_sizes, int n_in,
                              void* d_out, int out_size, void* d_ws, size_t ws_size,
                              hipStream_t stream) {
    const float* x  = (const float*)d_in[0];
    const float* w0 = (const float*)d_in[1];
    const float* w1 = (const float*)d_in[2];
    const float* w2 = (const float*)d_in[3];
    float* out = (float*)d_out;

    int n = in_sizes[0] / FEAT;
    int grid = (n + 15) / 16;
    dim3 blk(256);

    eq_linear_kernel<1, 0, 4>  <<<grid, blk, 0, stream>>>(x, w0, out, n);
    eq_linear_kernel<3, 128, 4><<<grid, blk, 0, stream>>>(x, w1, out, n);
    eq_linear_kernel<5, 512, 2><<<grid, blk, 0, stream>>>(x, w2, out, n);
}

// Round 4
// 805.140 us; speedup vs baseline: 1.0466x; 1.0466x over previous
//
#include <hip/hip_runtime.h>

// Block-diagonal equivariant linear on MI355X.
// out[n, OFF + w*D + i] = ALPHA * sum_u x[n, OFF + u*D + i] * W[u, w]
//
// v3 (resubmit x2; rounds 2-3 were broker timeouts, kernel never ran):
// drop the LDS out-staging tile entirely. Lane l16 owns output col w,
// and the D component accumulators live in registers, so each lane holds
// D *consecutive* output dwords per row -> direct per-lane packed store
// (memcpy -> dwordx4+dword, align-4 OK on gfx950). This removes 41 KB LDS
// (D=5: 2 -> 4 blocks/CU), one barrier, and the whole drain pass.
// Stage phase split: issue all x loads -> build W frags (hides x latency)
// -> convert + deinterleave into bf16 planes.

typedef __attribute__((ext_vector_type(8))) short short8;
typedef __attribute__((ext_vector_type(4))) float floatx4;

#define ALPHA 0.08838834764831845f
#define FEAT 1152

__device__ inline unsigned short bf16_rne(float f) {
    unsigned int u = __float_as_uint(f);
    unsigned int r = u + 0x7fffu + ((u >> 16) & 1u);
    return (unsigned short)(r >> 16);
}

template <int D, int OFF>
__launch_bounds__(256, 4)
__global__ void eq_linear_kernel(const float* __restrict__ x,
                                 const float* __restrict__ wmat,
                                 float* __restrict__ out, int n) {
    constexpr int C   = 128 * D;        // columns in this irrep block
    constexpr int C4  = C / 4;
    constexpr int R   = 16;             // rows per workgroup (one M-tile)
    constexpr int AP  = 136;            // plane row pitch (elems, 272B -> bank rotation)
    constexpr int APL = R * AP + 8;     // plane stride (+16B skew)

    __shared__ unsigned short xs[D * APL];   // D=5: 21.8 KB -> 4 blocks/CU

    const int tid  = threadIdx.x;
    const int lane = tid & 63;
    const int wave = tid >> 6;
    const int l16  = lane & 15;
    const int quad = lane >> 4;
    const int rowbase = blockIdx.x * R;

    // ---- phase 1: issue all x-tile loads (coalesced float4) ----
    constexpr int ITERS = (R * C4) / 256;   // 2 / 6 / 10 for D = 1/3/5
    floatx4 xv[ITERS];
#pragma unroll
    for (int it = 0; it < ITERS; ++it) {
        int idx = tid + it * 256;
        int r  = idx / C4;                  // compile-time divisor -> magic mul
        int c4 = idx - r * C4;
        xv[it] = floatx4{0.f, 0.f, 0.f, 0.f};
        if (rowbase + r < n) {
            xv[it] = *(reinterpret_cast<const floatx4*>(
                       x + (size_t)(rowbase + r) * FEAT + OFF) + c4);
        }
    }

    // ---- phase 2: B fragments from W (L2-hot) while x loads are in flight ----
    short8 bfrag[2][4];
#pragma unroll
    for (int ntl = 0; ntl < 2; ++ntl) {
        int wcol = (wave * 2 + ntl) * 16 + l16;
#pragma unroll
        for (int k = 0; k < 4; ++k) {
            int u0 = k * 32 + quad * 8;
            short8 f;
#pragma unroll
            for (int j = 0; j < 8; ++j) {
                f[j] = (short)bf16_rne(wmat[(u0 + j) * 128 + wcol]);
            }
            bfrag[ntl][k] = f;
        }
    }

    // ---- phase 3: convert + deinterleave x into bf16 planes ----
#pragma unroll
    for (int it = 0; it < ITERS; ++it) {
        int idx = tid + it * 256;
        int r  = idx / C4;
        int c4 = idx - r * C4;
        floatx4 v = xv[it];
        if (D == 1) {
            unsigned int p0 = (unsigned int)bf16_rne(v.x) | ((unsigned int)bf16_rne(v.y) << 16);
            unsigned int p1 = (unsigned int)bf16_rne(v.z) | ((unsigned int)bf16_rne(v.w) << 16);
            unsigned int* lp = reinterpret_cast<unsigned int*>(&xs[r * AP + c4 * 4]);
            lp[0] = p0;
            lp[1] = p1;
        } else {
#pragma unroll
            for (int j = 0; j < 4; ++j) {
                int c = 4 * c4 + j;
                int u = c / D;              // compile-time divisor
                int i = c - u * D;
                xs[i * APL + r * AP + u] = bf16_rne(v[j]);
            }
        }
    }

    __syncthreads();

    // ---- compute: A-frag = one ds_read_b128 per (i,k); all D accs live ----
    floatx4 acc[2][D];
#pragma unroll
    for (int ntl = 0; ntl < 2; ++ntl)
#pragma unroll
        for (int i = 0; i < D; ++i)
            acc[ntl][i] = floatx4{0.f, 0.f, 0.f, 0.f};

#pragma unroll
    for (int i = 0; i < D; ++i) {
#pragma unroll
        for (int k = 0; k < 4; ++k) {
            const short8 a = *reinterpret_cast<const short8*>(
                &xs[i * APL + l16 * AP + k * 32 + quad * 8]);
            acc[0][i] = __builtin_amdgcn_mfma_f32_16x16x32_bf16(a, bfrag[0][k], acc[0][i], 0, 0, 0);
            acc[1][i] = __builtin_amdgcn_mfma_f32_16x16x32_bf16(a, bfrag[1][k], acc[1][i], 0, 0, 0);
        }
    }

    // ---- store: per-lane D consecutive dwords (packed, align-4) ----
#pragma unroll
    for (int ntl = 0; ntl < 2; ++ntl) {
        const int wc = (wave * 2 + ntl) * 16 + l16;
#pragma unroll
        for (int r = 0; r < 4; ++r) {
            const int row = rowbase + quad * 4 + r;
            if (row < n) {
                float* p = out + (size_t)row * FEAT + OFF + wc * D;
                float s[D];
#pragma unroll
                for (int i = 0; i < D; ++i) s[i] = acc[ntl][i][r] * ALPHA;
                __builtin_memcpy(p, s, sizeof(s));   // D=5 -> dwordx4+dword, D=3 -> dwordx2+dword
            }
        }
    }
}

extern "C" void kernel_launch(void* const* d_in, const int* in_sizes, int n_in,
                              void* d_out, int out_size, void* d_ws, size_t ws_size,
                              hipStream_t stream) {
    const float* x  = (const float*)d_in[0];
    const float* w0 = (const float*)d_in[1];
    const float* w1 = (const float*)d_in[2];
    const float* w2 = (const float*)d_in[3];
    float* out = (float*)d_out;

    int n = in_sizes[0] / FEAT;
    int grid = (n + 15) / 16;
    dim3 blk(256);

    eq_linear_kernel<1, 0>  <<<grid, blk, 0, stream>>>(x, w0, out, n);
    eq_linear_kernel<3, 128><<<grid, blk, 0, stream>>>(x, w1, out, n);
    eq_linear_kernel<5, 512><<<grid, blk, 0, stream>>>(x, w2, out, n);
}